// Round 5
// baseline (8576.155 us; speedup 1.0000x reference)
//
#include <hip/hip_runtime.h>
#include <math.h>
#include <stdint.h>

// SPINN forward, fp32, persistent kernel, 2 grid barriers/step. NO inline asm:
// all cross-XCD data via __hip_atomic_* (agent scope) intrinsics, all patterns
// lane-contiguous (no sector amplification). GEMM epilogue bounces through LDS.
// Phase A: GEMM1 (28xK64) + GEMM2a (8xK128) work-steal units.
// Phase BD: gate-reduce + tracker cell + logits/argmax + track-GEMV + TreeLSTM
//           node + stack update + next-X gather (per-row block).

#define B_ 128
#define CAP 42
#define XW 1792   // X row: [buf_h 0:512 | s1_h 512:1024 | s2_h 1024:1536 | th_old 1536:1792]
#define NBLK 512
#define NTHR 256
#define SYNC_INTS 4096

typedef float v4f __attribute__((ext_vector_type(4)));

__device__ __forceinline__ float sigm(float x) { return 1.f / (1.f + expf(-x)); }

__device__ __forceinline__ float cload(const float* p) {
    return __hip_atomic_load(p, __ATOMIC_RELAXED, __HIP_MEMORY_SCOPE_AGENT);
}
__device__ __forceinline__ void cstore(float* p, float v) {
    __hip_atomic_store(p, v, __ATOMIC_RELAXED, __HIP_MEMORY_SCOPE_AGENT);
}
__device__ __forceinline__ void cstore64(float* p, float a, float b) {
    uint64_t v;
    float t2[2] = {a, b};
    __builtin_memcpy(&v, t2, 8);
    __hip_atomic_store((uint64_t*)p, v, __ATOMIC_RELAXED, __HIP_MEMORY_SCOPE_AGENT);
}

__global__ void k_zero(int* sync) {
    for (int i = threadIdx.x; i < SYNC_INTS; i += 256) sync[i] = 0;
}

// sync layout: [leaf r*256, r<8][2048 root][2049 release][2056.. steal ctrs]
__device__ __forceinline__ void grid_barrier(int* sync, int idx, int tid, int bid) {
    __syncthreads();   // compiler drains vmcnt before s_barrier
    if (tid == 0) {
        int* leaf = sync + (bid & 7) * 256;
        int* root = sync + 2048;
        int* release = sync + 2049;
        int prev = __hip_atomic_fetch_add(leaf, 1, __ATOMIC_RELAXED, __HIP_MEMORY_SCOPE_AGENT);
        if (prev == idx * (NBLK / 8) - 1) {
            int r = __hip_atomic_fetch_add(root, 1, __ATOMIC_RELAXED, __HIP_MEMORY_SCOPE_AGENT);
            if (r == idx * 8 - 1) {
                __hip_atomic_store(release, idx, __ATOMIC_RELAXED, __HIP_MEMORY_SCOPE_AGENT);
            }
        }
        while (__hip_atomic_load(sync + 2049, __ATOMIC_RELAXED, __HIP_MEMORY_SCOPE_AGENT) < idx) {
            __builtin_amdgcn_s_sleep(4);
        }
    }
    __syncthreads();
}

// one GEMM unit: 128 rows x 128 cols x KS, math bit-exact to R1/R3
// smem: As[32][132] at 0 (4224 floats), Wsh[32][136] at 4224 (4352 floats)
__device__ void gemm_unit(const float* __restrict__ Xm, const float* __restrict__ WT,
                          float* __restrict__ dst, int N, int n0, int krow0, int acol0,
                          int KS, float* smem, int tid) {
    float (*As)[132] = (float(*)[132])smem;
    float (*Wsh)[136] = (float(*)[136])(smem + 4224);
    const int tm = tid >> 4, tn = tid & 15;
    const int kk_s = tid & 31, mg = tid >> 5;   // A staging: lane-contiguous over kk
    const int wk = tid >> 3, wf = tid & 7;      // W staging
    float acc[8][8];
#pragma unroll
    for (int i = 0; i < 8; i++)
#pragma unroll
        for (int j = 0; j < 8; j++) acc[i][j] = 0.f;

    for (int ki = 0; ki < KS; ki += 32) {
        __syncthreads();
        // stage A: coherent scalar loads, 32 consecutive floats per 32 lanes
        float tmp[16];
#pragma unroll
        for (int r = 0; r < 16; r++)
            tmp[r] = cload(Xm + (size_t)(mg + 8 * r) * XW + acol0 + ki + kk_s);
        // stage W: plain cached float4 (L2-resident weights)
        {
            const float4* src = (const float4*)(WT + (size_t)(krow0 + ki + wk) * N + n0);
            float4 w0 = src[wf], w1 = src[wf + 8], w2 = src[wf + 16], w3 = src[wf + 24];
            *(float4*)&Wsh[wk][4 * wf]      = w0;
            *(float4*)&Wsh[wk][4 * wf + 32] = w1;
            *(float4*)&Wsh[wk][4 * wf + 64] = w2;
            *(float4*)&Wsh[wk][4 * wf + 96] = w3;
        }
#pragma unroll
        for (int r = 0; r < 16; r++) As[kk_s][mg + 8 * r] = tmp[r];
        __syncthreads();
#pragma unroll 4
        for (int kk = 0; kk < 32; kk++) {
            float a[8], w[8];
            *(v4f*)&a[0] = *(const v4f*)&As[kk][tm * 4];
            *(v4f*)&a[4] = *(const v4f*)&As[kk][64 + tm * 4];
            *(v4f*)&w[0] = *(const v4f*)&Wsh[kk][tn * 4];
            *(v4f*)&w[4] = *(const v4f*)&Wsh[kk][64 + tn * 4];
#pragma unroll
            for (int i = 0; i < 8; i++)
#pragma unroll
                for (int j = 0; j < 8; j++) acc[i][j] += a[i] * w[j];
        }
    }
    // epilogue: LDS bounce, then lane-contiguous 8B coherent stores (no amplification)
    float (*buf)[136] = (float(*)[136])smem;
    const int c2 = tid & 63, r0 = tid >> 6;
#pragma unroll
    for (int ch = 0; ch < 4; ch++) {   // rows [32ch, 32ch+32)
        __syncthreads();
        if (ch < 2) {
            if ((tm >> 3) == ch) {
                int tmr = tm - 8 * ch;
#pragma unroll
                for (int i = 0; i < 4; i++) {
                    int rr = tmr * 4 + i;
                    *(float4*)&buf[rr][tn * 4]      = *(float4*)&acc[i][0];
                    *(float4*)&buf[rr][64 + tn * 4] = *(float4*)&acc[i][4];
                }
            }
        } else {
            if ((tm >> 3) == ch - 2) {
                int tmr = tm - 8 * (ch - 2);
#pragma unroll
                for (int i = 4; i < 8; i++) {
                    int rr = tmr * 4 + (i - 4);
                    *(float4*)&buf[rr][tn * 4]      = *(float4*)&acc[i][0];
                    *(float4*)&buf[rr][64 + tn * 4] = *(float4*)&acc[i][4];
                }
            }
        }
        __syncthreads();
#pragma unroll
        for (int rr = r0; rr < 32; rr += 4) {
            cstore64(dst + (size_t)(32 * ch + rr) * N + n0 + 2 * c2,
                     buf[rr][2 * c2], buf[rr][2 * c2 + 1]);
        }
    }
}

__global__ __launch_bounds__(NTHR, 2) void k_spinn(
    const float* __restrict__ buffers, const float* __restrict__ W_left,
    const float* __restrict__ b_left, const float* __restrict__ W_right,
    const float* __restrict__ W_track, const float* __restrict__ W_ih,
    const float* __restrict__ W_hh, const float* __restrict__ b_ih,
    const float* __restrict__ b_hh, const float* __restrict__ W_trans,
    const float* __restrict__ b_trans, float* __restrict__ out,
    float* __restrict__ W1T, float* __restrict__ W2T, float* __restrict__ b1,
    float* __restrict__ X, float* __restrict__ tc,
    float* __restrict__ g1part, float* __restrict__ g2apart,
    float* __restrict__ stack, int* __restrict__ sptr, int* __restrict__ blen,
    int* __restrict__ sync) {
    __shared__ float smem[8576];      // 34304 B: As 4224 + Ws 4352
    __shared__ int s_u;
    __shared__ int s_tr;
    int* ctr = sync + 2056;
    const int bid = blockIdx.x, tid = threadIdx.x;
    int barid = 0;

    // ---- init: weight repack + state init ----
    {
        const size_t n1 = 1792ull * 1024ull;
        const size_t n2 = 1280ull * 2560ull;
        const size_t total = n1 + n2 + 1024;
        for (size_t idx = (size_t)bid * NTHR + tid; idx < total; idx += (size_t)NBLK * NTHR) {
            if (idx < n1) {
                int k = (int)(idx >> 10), n = (int)(idx & 1023);
                W1T[idx] = (k < 1536) ? W_ih[(size_t)n * 1536 + k]
                                      : W_hh[(size_t)n * 256 + (k - 1536)];
            } else if (idx < n1 + n2) {
                size_t r = idx - n1;
                int k = (int)(r / 2560), n = (int)(r % 2560);
                float v;
                if (k < 512)       v = W_right[(size_t)n * 512 + k];
                else if (k < 1024) v = W_left [(size_t)n * 512 + (k - 512)];
                else               v = W_track[(size_t)n * 256 + (k - 1024)];
                W2T[r] = v;
            } else {
                int i = (int)(idx - n1 - n2);
                b1[i] = b_ih[i] + b_hh[i];
            }
        }
        if (bid < 128) {
            int b = bid;
            const float* b0 = buffers + (size_t)b * 40 * 1024;
            const float* btop = b0 + 39 * 1024;
            float* stk = stack + (size_t)b * CAP * 1024;
            for (int j = tid; j < 1024; j += 256) { stk[j] = b0[j]; stk[1024 + j] = b0[j]; }
            float* Xb = X + (size_t)b * XW;
            for (int j = tid; j < 512; j += 256) {
                Xb[j] = btop[j]; Xb[512 + j] = b0[j]; Xb[1024 + j] = b0[j];
            }
            Xb[1536 + tid] = 0.f;
            tc[b * 256 + tid] = 0.f;
            if (tid == 0) { sptr[b] = 2; blen[b] = 40; }
        }
    }
    __syncthreads();
    if (tid == 0) __builtin_amdgcn_fence(__ATOMIC_RELEASE, "agent");  // publish init (R3-proven)
    grid_barrier(sync, ++barid, tid, bid);

#pragma unroll 1
    for (int s = 0; s < 64; s++) {
        // ---------- Phase A: GEMM2a (160 units K128, first) + GEMM1 (224 units K64) ----------
        {
            int* c = &ctr[s];
            for (;;) {
                __syncthreads();
                if (tid == 0) s_u = atomicAdd(c, 1);
                __syncthreads();
                int u = s_u;
                if (u >= 384) break;
                if (u < 160) {          // GEMM2a: s1h|s2h, K=1024, 8 slots of K128
                    int n0 = (u % 20) * 128, kc = u / 20;
                    gemm_unit(X, W2T, g2apart + (size_t)kc * 327680, 2560,
                              n0, kc * 128, 512 + kc * 128, 128, smem, tid);
                } else {                // GEMM1: K=1792, 28 slots of K64
                    int v = u - 160;
                    int n0 = (v & 7) * 128, kc = v >> 3;
                    gemm_unit(X, W1T, g1part + (size_t)kc * 131072, 1024,
                              n0, kc * 64, kc * 64, 64, smem, tid);
                }
            }
        }
        grid_barrier(sync, ++barid, tid, bid);

        // ---------- Phase BD (blocks 0..127) ----------
        if (bid < 128) {
            const int b = bid, t = tid;
            float* red   = smem;           // [256][4]
            float* th_l  = smem + 1024;    // 256
            float* nodeh = smem + 1280;    // 512
            float* nodec = smem + 1792;    // 512

            // gate reduce, kc ascending 0..27 (bit-exact to R1/R3 order)
            const float* gp = g1part + (size_t)b * 1024;
            float gi = b1[t], gf = b1[256 + t], gg = b1[512 + t], go = b1[768 + t];
#pragma unroll
            for (int g4 = 0; g4 < 4; g4++) {
                float ra[7], rb[7], rc[7], rd[7];
#pragma unroll
                for (int q = 0; q < 7; q++) {
                    const float* p = gp + (size_t)(g4 * 7 + q) * 131072;
                    ra[q] = cload(p + t); rb[q] = cload(p + 256 + t);
                    rc[q] = cload(p + 512 + t); rd[q] = cload(p + 768 + t);
                }
#pragma unroll
                for (int q = 0; q < 7; q++) { gi += ra[q]; gf += rb[q]; gg += rc[q]; go += rd[q]; }
            }
            float tcv = tc[b * 256 + t];
            float tcn = sigm(gf) * tcv + sigm(gi) * tanhf(gg);
            float thn = sigm(go) * tanhf(tcn);
            tc[b * 256 + t] = tcn;
            cstore(X + (size_t)b * XW + 1536 + t, thn);   // th_old for next step's GEMM1
            th_l[t] = thn;

            red[t * 4 + 0] = thn * W_trans[t];
            red[t * 4 + 1] = thn * W_trans[256 + t];
            red[t * 4 + 2] = thn * W_trans[512 + t];
            red[t * 4 + 3] = thn * W_trans[768 + t];
            __syncthreads();
            for (int off = 128; off > 0; off >>= 1) {
                if (t < off) {
                    red[t * 4 + 0] += red[(t + off) * 4 + 0];
                    red[t * 4 + 1] += red[(t + off) * 4 + 1];
                    red[t * 4 + 2] += red[(t + off) * 4 + 2];
                    red[t * 4 + 3] += red[(t + off) * 4 + 3];
                }
                __syncthreads();
            }
            if (t == 0) {
                int tr = 0; float best = -1e30f;
#pragma unroll
                for (int l = 0; l < 4; l++) {
                    float lg = red[l] + b_trans[l];
                    if (lg > best) { best = lg; tr = l; }   // first-max = jnp.argmax
                    out[(size_t)s * 512 + b * 4 + l] = lg;
                }
                s_tr = tr;
            }
            __syncthreads();

            const int tr = s_tr;
            const int sp = sptr[b], bl = blen[b];
            const bool do_shift = (tr == 3) && (bl > 2);
            const bool do_red   = (tr == 2) && (sp > 3);
            float* stk = stack + (size_t)b * CAP * 1024;   // same-block only -> cached

            if (do_red) {
#pragma unroll
                for (int jj = 0; jj < 2; jj++) {
                    int e = t + 256 * jj;
                    float s1c = stk[(size_t)(sp - 1) * 1024 + 512 + e];
                    float s2c = stk[(size_t)(sp - 2) * 1024 + 512 + e];
                    float v[5];
#pragma unroll
                    for (int g = 0; g < 5; g++) {
                        int gc = g * 512 + e;
                        float p8[8];
#pragma unroll
                        for (int kc = 0; kc < 8; kc++)
                            p8[kc] = cload(g2apart + (size_t)kc * 327680 + (size_t)b * 2560 + gc);
                        float a = b_left[gc];
#pragma unroll
                        for (int kc = 0; kc < 8; kc++) a += p8[kc];
                        // track term: 8 chunks of K32, serial within (bit-exact to R3 phase C+D)
#pragma unroll
                        for (int kc = 0; kc < 8; kc++) {
                            float trp = 0.f;
#pragma unroll 4
                            for (int k2 = 0; k2 < 32; k2++)
                                trp += th_l[32 * kc + k2] *
                                       W2T[(size_t)(1024 + 32 * kc + k2) * 2560 + gc];
                            a += trp;
                        }
                        v[g] = a;
                    }
                    float c = tanhf(v[0]) * sigm(v[1]) + sigm(v[2]) * s2c + sigm(v[3]) * s1c;
                    float h = sigm(v[4]) * tanhf(c);
                    nodeh[e] = h; nodec[e] = c;
                }
            }
            __syncthreads();
            if (do_red) {
                float* dst = stk + (size_t)(sp - 2) * 1024;
                for (int j = t; j < 512; j += 256) { dst[j] = nodeh[j]; dst[512 + j] = nodec[j]; }
            }
            if (do_shift) {
                const float* bt = buffers + ((size_t)b * 40 + (bl - 1)) * 1024;
                float* dst = stk + (size_t)sp * 1024;
                for (int j = t; j < 1024; j += 256) dst[j] = bt[j];
            }
            int spn = sp + (do_shift ? 1 : 0) - (do_red ? 1 : 0);
            int bln = bl - (do_shift ? 1 : 0);
            if (t == 0) { sptr[b] = spn; blen[b] = bln; }
            __syncthreads();

            // gather next X: coherent 8B stores, lane-contiguous
            float* Xb = X + (size_t)b * XW;
            {   // buf_h = buffers[b][bln-1][:512]
                const float* btn = buffers + ((size_t)b * 40 + (bln - 1)) * 1024;
                cstore64(Xb + 2 * t, btn[2 * t], btn[2 * t + 1]);
            }
            {   // s1' = stack[spn-1] h-part
                float a, c;
                if (do_red) { a = nodeh[2 * t]; c = nodeh[2 * t + 1]; }
                else if (do_shift) {
                    const float* src = buffers + ((size_t)b * 40 + (bl - 1)) * 1024;
                    a = src[2 * t]; c = src[2 * t + 1];
                } else {
                    const float* src = stk + (size_t)(sp - 1) * 1024;
                    a = src[2 * t]; c = src[2 * t + 1];
                }
                cstore64(Xb + 512 + 2 * t, a, c);
            }
            {   // s2' = stack[spn-2] h-part (slot untouched in all cases)
                const float* src = stk + (size_t)(spn - 2) * 1024;
                cstore64(Xb + 1024 + 2 * t, src[2 * t], src[2 * t + 1]);
            }
        }
        grid_barrier(sync, ++barid, tid, bid);
    }
}

extern "C" void kernel_launch(void* const* d_in, const int* in_sizes, int n_in,
                              void* d_out, int out_size, void* d_ws, size_t ws_size,
                              hipStream_t stream) {
    const float* buffers = (const float*)d_in[0];
    const float* W_left  = (const float*)d_in[1];
    const float* b_left  = (const float*)d_in[2];
    const float* W_right = (const float*)d_in[3];
    const float* W_track = (const float*)d_in[4];
    const float* W_ih    = (const float*)d_in[5];
    const float* W_hh    = (const float*)d_in[6];
    const float* b_ih    = (const float*)d_in[7];
    const float* b_hh    = (const float*)d_in[8];
    const float* W_trans = (const float*)d_in[9];
    const float* b_trans = (const float*)d_in[10];
    float* out = (float*)d_out;

    float* ws = (float*)d_ws;
    size_t off = 0;
    float* W1T     = ws + off; off += 1792ull * 1024;            // 1,835,008
    float* W2T     = ws + off; off += 1280ull * 2560;            // 3,276,800
    float* b1      = ws + off; off += 1024;
    float* X       = ws + off; off += (size_t)B_ * XW;           // 229,376
    float* tc      = ws + off; off += (size_t)B_ * 256;
    float* g1part  = ws + off; off += 28ull * 128 * 1024;        // 3,670,016
    float* g2apart = ws + off; off += 8ull * 128 * 2560;         // 2,621,440
    float* stack   = ws + off; off += (size_t)B_ * CAP * 1024;   // 5,505,024
    int*   sptr    = (int*)(ws + off); off += 128;
    int*   blen    = (int*)(ws + off); off += 128;
    int*   sync    = (int*)(ws + off); off += SYNC_INTS;

    k_zero<<<1, 256, 0, stream>>>(sync);
    k_spinn<<<NBLK, NTHR, 0, stream>>>(buffers, W_left, b_left, W_right, W_track,
                                       W_ih, W_hh, b_ih, b_hh, W_trans, b_trans, out,
                                       W1T, W2T, b1, X, tc, g1part, g2apart, stack,
                                       sptr, blen, sync);
    (void)in_sizes; (void)n_in; (void)out_size; (void)ws_size;
}

// Round 6
// 4863.543 us; speedup vs baseline: 1.7634x; 1.7634x over previous
//
#include <hip/hip_runtime.h>
#include <math.h>
#include <stdint.h>

// SPINN forward, fp32, persistent kernel, STATIC work assignment (no work-steal
// atomics), 4 grid barriers/step with replicated release words.
// Phase A: gates GEMM (224 units: 28 kc x 8 n0, K64) + s1s2 GEMM (160 units:
//          8 kc x 20 n0, K128)  -> blocks 0..223 / 224..383
// Phase B: gate-reduce + tracker cell + logits + argmax (blocks 0..127)
// Phase C: track GEMM (160 units: 8 kc x 20 n0, K32) -> blocks 0..159
// Phase D: TreeLSTM node + stack + next-X gather (blocks 0..127)
// Coherence: weights/stack/tc/buffers plain-cached (same-block or read-only);
// partials & X via __hip_atomic_* agent-scope, lane-contiguous (R5-proven).

#define B_ 128
#define CAP 42
#define XW 1792   // X row: [buf_h 0:512 | s1_h 512:1024 | s2_h 1024:1536 | th 1536:1792]
#define NBLK 384
#define NTHR 256
#define SYNC_INTS 4096

typedef float v4f __attribute__((ext_vector_type(4)));

__device__ __forceinline__ float sigm(float x) { return 1.f / (1.f + expf(-x)); }

__device__ __forceinline__ float cload(const float* p) {
    return __hip_atomic_load(p, __ATOMIC_RELAXED, __HIP_MEMORY_SCOPE_AGENT);
}
__device__ __forceinline__ void cstore(float* p, float v) {
    __hip_atomic_store(p, v, __ATOMIC_RELAXED, __HIP_MEMORY_SCOPE_AGENT);
}
__device__ __forceinline__ void cstore64(float* p, float a, float b) {
    uint64_t v;
    float t2[2] = {a, b};
    __builtin_memcpy(&v, t2, 8);
    __hip_atomic_store((uint64_t*)p, v, __ATOMIC_RELAXED, __HIP_MEMORY_SCOPE_AGENT);
}

__global__ void k_zero(int* sync) {
    for (int i = threadIdx.x; i < SYNC_INTS; i += 256) sync[i] = 0;
}

// sync: leaf r at r*256 (r<8), root at 2048, release replicas at 2112 + r*64
__device__ __forceinline__ void grid_barrier(int* sync, int idx, int tid, int bid) {
    __syncthreads();   // drains vmcnt before s_barrier
    if (tid == 0) {
        const int lf = bid & 7;
        int prev = __hip_atomic_fetch_add(sync + lf * 256, 1, __ATOMIC_RELAXED,
                                          __HIP_MEMORY_SCOPE_AGENT);
        if (prev == idx * (NBLK / 8) - 1) {
            int r = __hip_atomic_fetch_add(sync + 2048, 1, __ATOMIC_RELAXED,
                                           __HIP_MEMORY_SCOPE_AGENT);
            if (r == idx * 8 - 1) {
#pragma unroll
                for (int q = 0; q < 8; q++)
                    __hip_atomic_store(sync + 2112 + q * 64, idx, __ATOMIC_RELAXED,
                                       __HIP_MEMORY_SCOPE_AGENT);
            }
        }
        while (__hip_atomic_load(sync + 2112 + lf * 64, __ATOMIC_RELAXED,
                                 __HIP_MEMORY_SCOPE_AGENT) < idx) {
            __builtin_amdgcn_s_sleep(2);
        }
    }
    __syncthreads();
}

// one GEMM unit: 128 rows x 128 cols x KS, math bit-exact to R1/R3/R5
// smem: As[32][132] at 0 (4224 floats), Wsh[32][136] at 4224 (4352 floats)
__device__ void gemm_unit(const float* __restrict__ Xm, const float* __restrict__ WT,
                          float* __restrict__ dst, int N, int n0, int krow0, int acol0,
                          int KS, float* smem, int tid) {
    float (*As)[132] = (float(*)[132])smem;
    float (*Wsh)[136] = (float(*)[136])(smem + 4224);
    const int tm = tid >> 4, tn = tid & 15;
    const int kk_s = tid & 31, mg = tid >> 5;   // A staging: lane-contiguous over kk
    const int wk = tid >> 3, wf = tid & 7;      // W staging
    float acc[8][8];
#pragma unroll
    for (int i = 0; i < 8; i++)
#pragma unroll
        for (int j = 0; j < 8; j++) acc[i][j] = 0.f;

    for (int ki = 0; ki < KS; ki += 32) {
        __syncthreads();
        float tmp[16];
#pragma unroll
        for (int r = 0; r < 16; r++)
            tmp[r] = cload(Xm + (size_t)(mg + 8 * r) * XW + acol0 + ki + kk_s);
        {
            const float4* src = (const float4*)(WT + (size_t)(krow0 + ki + wk) * N + n0);
            float4 w0 = src[wf], w1 = src[wf + 8], w2 = src[wf + 16], w3 = src[wf + 24];
            *(float4*)&Wsh[wk][4 * wf]      = w0;
            *(float4*)&Wsh[wk][4 * wf + 32] = w1;
            *(float4*)&Wsh[wk][4 * wf + 64] = w2;
            *(float4*)&Wsh[wk][4 * wf + 96] = w3;
        }
#pragma unroll
        for (int r = 0; r < 16; r++) As[kk_s][mg + 8 * r] = tmp[r];
        __syncthreads();
#pragma unroll 4
        for (int kk = 0; kk < 32; kk++) {
            float a[8], w[8];
            *(v4f*)&a[0] = *(const v4f*)&As[kk][tm * 4];
            *(v4f*)&a[4] = *(const v4f*)&As[kk][64 + tm * 4];
            *(v4f*)&w[0] = *(const v4f*)&Wsh[kk][tn * 4];
            *(v4f*)&w[4] = *(const v4f*)&Wsh[kk][64 + tn * 4];
#pragma unroll
            for (int i = 0; i < 8; i++)
#pragma unroll
                for (int j = 0; j < 8; j++) acc[i][j] += a[i] * w[j];
        }
    }
    // epilogue: LDS bounce, then lane-contiguous 8B coherent stores (R5-proven)
    float (*buf)[136] = (float(*)[136])smem;
    const int c2 = tid & 63, r0 = tid >> 6;
#pragma unroll
    for (int ch = 0; ch < 4; ch++) {
        __syncthreads();
        if (ch < 2) {
            if ((tm >> 3) == ch) {
                int tmr = tm - 8 * ch;
#pragma unroll
                for (int i = 0; i < 4; i++) {
                    int rr = tmr * 4 + i;
                    *(float4*)&buf[rr][tn * 4]      = *(float4*)&acc[i][0];
                    *(float4*)&buf[rr][64 + tn * 4] = *(float4*)&acc[i][4];
                }
            }
        } else {
            if ((tm >> 3) == ch - 2) {
                int tmr = tm - 8 * (ch - 2);
#pragma unroll
                for (int i = 4; i < 8; i++) {
                    int rr = tmr * 4 + (i - 4);
                    *(float4*)&buf[rr][tn * 4]      = *(float4*)&acc[i][0];
                    *(float4*)&buf[rr][64 + tn * 4] = *(float4*)&acc[i][4];
                }
            }
        }
        __syncthreads();
#pragma unroll
        for (int rr = r0; rr < 32; rr += 4) {
            cstore64(dst + (size_t)(32 * ch + rr) * N + n0 + 2 * c2,
                     buf[rr][2 * c2], buf[rr][2 * c2 + 1]);
        }
    }
}

__global__ __launch_bounds__(NTHR, 2) void k_spinn(
    const float* __restrict__ buffers, const float* __restrict__ W_left,
    const float* __restrict__ b_left, const float* __restrict__ W_right,
    const float* __restrict__ W_track, const float* __restrict__ W_ih,
    const float* __restrict__ W_hh, const float* __restrict__ b_ih,
    const float* __restrict__ b_hh, const float* __restrict__ W_trans,
    const float* __restrict__ b_trans, float* __restrict__ out,
    float* __restrict__ W1T, float* __restrict__ W2T, float* __restrict__ b1,
    float* __restrict__ X, float* __restrict__ tc,
    float* __restrict__ g1part, float* __restrict__ g2apart,
    float* __restrict__ tpart, float* __restrict__ stack,
    int* __restrict__ sptr, int* __restrict__ blen, int* __restrict__ sync) {
    __shared__ float smem[8576];      // 34304 B
    __shared__ int s_tr;              // survives barriers (B -> D, same block)
    const int bid = blockIdx.x, tid = threadIdx.x;
    int barid = 0;

    // ---- init: weight repack + state init ----
    {
        const size_t n1 = 1792ull * 1024ull;
        const size_t n2 = 1280ull * 2560ull;
        const size_t total = n1 + n2 + 1024;
        for (size_t idx = (size_t)bid * NTHR + tid; idx < total; idx += (size_t)NBLK * NTHR) {
            if (idx < n1) {
                int k = (int)(idx >> 10), n = (int)(idx & 1023);
                W1T[idx] = (k < 1536) ? W_ih[(size_t)n * 1536 + k]
                                      : W_hh[(size_t)n * 256 + (k - 1536)];
            } else if (idx < n1 + n2) {
                size_t r = idx - n1;
                int k = (int)(r / 2560), n = (int)(r % 2560);
                float v;
                if (k < 512)       v = W_right[(size_t)n * 512 + k];
                else if (k < 1024) v = W_left [(size_t)n * 512 + (k - 512)];
                else               v = W_track[(size_t)n * 256 + (k - 1024)];
                W2T[r] = v;
            } else {
                int i = (int)(idx - n1 - n2);
                b1[i] = b_ih[i] + b_hh[i];
            }
        }
        if (bid < 128) {
            int b = bid;
            const float* b0 = buffers + (size_t)b * 40 * 1024;
            const float* btop = b0 + 39 * 1024;
            float* stk = stack + (size_t)b * CAP * 1024;
            for (int j = tid; j < 1024; j += 256) { stk[j] = b0[j]; stk[1024 + j] = b0[j]; }
            float* Xb = X + (size_t)b * XW;
            for (int j = tid; j < 512; j += 256) {
                Xb[j] = btop[j]; Xb[512 + j] = b0[j]; Xb[1024 + j] = b0[j];
            }
            Xb[1536 + tid] = 0.f;
            tc[b * 256 + tid] = 0.f;
            if (tid == 0) { sptr[b] = 2; blen[b] = 40; }
        }
    }
    __syncthreads();
    if (tid == 0) __builtin_amdgcn_fence(__ATOMIC_RELEASE, "agent");  // publish init once
    grid_barrier(sync, ++barid, tid, bid);

#pragma unroll 1
    for (int s = 0; s < 64; s++) {
        // ---------- Phase A: static units — gates (0..223), s1s2 (224..383) ----------
        if (bid < 224) {
            int n0 = (bid & 7) * 128, kc = bid >> 3;          // kc 0..27
            gemm_unit(X, W1T, g1part + (size_t)kc * 131072, 1024,
                      n0, kc * 64, kc * 64, 64, smem, tid);
        } else {
            int u = bid - 224;                                 // 0..159
            int n0 = (u % 20) * 128, kc = u / 20;              // kc 0..7
            gemm_unit(X, W2T, g2apart + (size_t)kc * 327680, 2560,
                      n0, kc * 128, 512 + kc * 128, 128, smem, tid);
        }
        grid_barrier(sync, ++barid, tid, bid);

        // ---------- Phase B (blocks 0..127): cell + logits + argmax ----------
        if (bid < 128) {
            const int b = bid, t = tid;
            const float* gp = g1part + (size_t)b * 1024;
            float gi = b1[t], gf = b1[256 + t], gg = b1[512 + t], go = b1[768 + t];
#pragma unroll
            for (int g4 = 0; g4 < 4; g4++) {
                float ra[7], rb[7], rc[7], rd[7];
#pragma unroll
                for (int q = 0; q < 7; q++) {
                    const float* p = gp + (size_t)(g4 * 7 + q) * 131072;
                    ra[q] = cload(p + t); rb[q] = cload(p + 256 + t);
                    rc[q] = cload(p + 512 + t); rd[q] = cload(p + 768 + t);
                }
#pragma unroll
                for (int q = 0; q < 7; q++) { gi += ra[q]; gf += rb[q]; gg += rc[q]; go += rd[q]; }
            }
            float tcv = tc[b * 256 + t];
            float tcn = sigm(gf) * tcv + sigm(gi) * tanhf(gg);
            float thn = sigm(go) * tanhf(tcn);
            tc[b * 256 + t] = tcn;
            cstore(X + (size_t)b * XW + 1536 + t, thn);   // th: read by C now, gates next step

            float* red = smem;   // [256][4]
            red[t * 4 + 0] = thn * W_trans[t];
            red[t * 4 + 1] = thn * W_trans[256 + t];
            red[t * 4 + 2] = thn * W_trans[512 + t];
            red[t * 4 + 3] = thn * W_trans[768 + t];
            __syncthreads();
            for (int off = 128; off > 0; off >>= 1) {
                if (t < off) {
                    red[t * 4 + 0] += red[(t + off) * 4 + 0];
                    red[t * 4 + 1] += red[(t + off) * 4 + 1];
                    red[t * 4 + 2] += red[(t + off) * 4 + 2];
                    red[t * 4 + 3] += red[(t + off) * 4 + 3];
                }
                __syncthreads();
            }
            if (t == 0) {
                int tr = 0; float best = -1e30f;
#pragma unroll
                for (int l = 0; l < 4; l++) {
                    float lg = red[l] + b_trans[l];
                    if (lg > best) { best = lg; tr = l; }   // first-max = jnp.argmax
                    out[(size_t)s * 512 + b * 4 + l] = lg;
                }
                s_tr = tr;
            }
        }
        grid_barrier(sync, ++barid, tid, bid);

        // ---------- Phase C: track GEMM, static units on blocks 0..159 ----------
        if (bid < 160) {
            int n0 = (bid % 20) * 128, kc = bid / 20;          // kc 0..7, K=32
            gemm_unit(X, W2T, tpart + (size_t)kc * 327680, 2560,
                      n0, 1024 + kc * 32, 1536 + kc * 32, 32, smem, tid);
        }
        grid_barrier(sync, ++barid, tid, bid);

        // ---------- Phase D (blocks 0..127): node + stack + next-X gather ----------
        if (bid < 128) {
            const int b = bid, t = tid;
            const int tr = s_tr;
            const int sp = sptr[b], bl = blen[b];
            const bool do_shift = (tr == 3) && (bl > 2);
            const bool do_red   = (tr == 2) && (sp > 3);
            float* stk = stack + (size_t)b * CAP * 1024;   // same-block only -> cached
            float* nodeh = smem + 1280;
            float* nodec = smem + 1792;

            if (do_red) {
#pragma unroll
                for (int jj = 0; jj < 2; jj++) {
                    int e = t + 256 * jj;
                    float s1c = stk[(size_t)(sp - 1) * 1024 + 512 + e];
                    float s2c = stk[(size_t)(sp - 2) * 1024 + 512 + e];
                    float v[5];
#pragma unroll
                    for (int g = 0; g < 5; g++) {
                        int gc = g * 512 + e;
                        float p8[8], q8[8];
#pragma unroll
                        for (int kc = 0; kc < 8; kc++)
                            p8[kc] = cload(g2apart + (size_t)kc * 327680 + (size_t)b * 2560 + gc);
#pragma unroll
                        for (int kc = 0; kc < 8; kc++)
                            q8[kc] = cload(tpart + (size_t)kc * 327680 + (size_t)b * 2560 + gc);
                        float a = b_left[gc];
#pragma unroll
                        for (int kc = 0; kc < 8; kc++) a += p8[kc];
#pragma unroll
                        for (int kc = 0; kc < 8; kc++) a += q8[kc];
                        v[g] = a;
                    }
                    float c = tanhf(v[0]) * sigm(v[1]) + sigm(v[2]) * s2c + sigm(v[3]) * s1c;
                    float h = sigm(v[4]) * tanhf(c);
                    nodeh[e] = h; nodec[e] = c;
                }
            }
            __syncthreads();
            if (do_red) {
                float* dst = stk + (size_t)(sp - 2) * 1024;
                for (int j = t; j < 512; j += 256) { dst[j] = nodeh[j]; dst[512 + j] = nodec[j]; }
            }
            if (do_shift) {
                const float* bt = buffers + ((size_t)b * 40 + (bl - 1)) * 1024;
                float* dst = stk + (size_t)sp * 1024;
                for (int j = t; j < 1024; j += 256) dst[j] = bt[j];
            }
            int spn = sp + (do_shift ? 1 : 0) - (do_red ? 1 : 0);
            int bln = bl - (do_shift ? 1 : 0);
            if (t == 0) { sptr[b] = spn; blen[b] = bln; }
            __syncthreads();

            // gather next X: coherent 8B lane-contiguous stores
            float* Xb = X + (size_t)b * XW;
            {
                const float* btn = buffers + ((size_t)b * 40 + (bln - 1)) * 1024;
                cstore64(Xb + 2 * t, btn[2 * t], btn[2 * t + 1]);
            }
            {
                float a, c;
                if (do_red) { a = nodeh[2 * t]; c = nodeh[2 * t + 1]; }
                else if (do_shift) {
                    const float* src = buffers + ((size_t)b * 40 + (bl - 1)) * 1024;
                    a = src[2 * t]; c = src[2 * t + 1];
                } else {
                    const float* src = stk + (size_t)(sp - 1) * 1024;
                    a = src[2 * t]; c = src[2 * t + 1];
                }
                cstore64(Xb + 512 + 2 * t, a, c);
            }
            {
                const float* src = stk + (size_t)(spn - 2) * 1024;
                cstore64(Xb + 1024 + 2 * t, src[2 * t], src[2 * t + 1]);
            }
        }
        grid_barrier(sync, ++barid, tid, bid);
    }
}

extern "C" void kernel_launch(void* const* d_in, const int* in_sizes, int n_in,
                              void* d_out, int out_size, void* d_ws, size_t ws_size,
                              hipStream_t stream) {
    const float* buffers = (const float*)d_in[0];
    const float* W_left  = (const float*)d_in[1];
    const float* b_left  = (const float*)d_in[2];
    const float* W_right = (const float*)d_in[3];
    const float* W_track = (const float*)d_in[4];
    const float* W_ih    = (const float*)d_in[5];
    const float* W_hh    = (const float*)d_in[6];
    const float* b_ih    = (const float*)d_in[7];
    const float* b_hh    = (const float*)d_in[8];
    const float* W_trans = (const float*)d_in[9];
    const float* b_trans = (const float*)d_in[10];
    float* out = (float*)d_out;

    float* ws = (float*)d_ws;
    size_t off = 0;
    float* W1T     = ws + off; off += 1792ull * 1024;            // 1,835,008
    float* W2T     = ws + off; off += 1280ull * 2560;            // 3,276,800
    float* b1      = ws + off; off += 1024;
    float* X       = ws + off; off += (size_t)B_ * XW;           // 229,376
    float* tc      = ws + off; off += (size_t)B_ * 256;
    float* g1part  = ws + off; off += 28ull * 128 * 1024;        // 3,670,016
    float* g2apart = ws + off; off += 8ull * 128 * 2560;         // 2,621,440
    float* tpart   = ws + off; off += 8ull * 128 * 2560;         // 2,621,440
    float* stack   = ws + off; off += (size_t)B_ * CAP * 1024;   // 5,505,024
    int*   sptr    = (int*)(ws + off); off += 128;
    int*   blen    = (int*)(ws + off); off += 128;
    int*   sync    = (int*)(ws + off); off += SYNC_INTS;

    k_zero<<<1, 256, 0, stream>>>(sync);
    k_spinn<<<NBLK, NTHR, 0, stream>>>(buffers, W_left, b_left, W_right, W_track,
                                       W_ih, W_hh, b_ih, b_hh, W_trans, b_trans, out,
                                       W1T, W2T, b1, X, tc, g1part, g2apart, tpart,
                                       stack, sptr, blen, sync);
    (void)in_sizes; (void)n_in; (void)out_size; (void)ws_size;
}